// Round 7
// baseline (42.766 us; speedup 1.0000x reference)
//
#include <hip/hip_runtime.h>

#define DIMS 64
#define KCB 512
#define OUT_Q 8388608   // 32*64*64*64

typedef float f32x4 __attribute__((ext_vector_type(4)));
typedef float f4    __attribute__((ext_vector_type(4)));
typedef short short8 __attribute__((ext_vector_type(8)));

// ws: float[0..512) per-WG partial loss sums. Nothing else.
// LDS per WG: f4[0..4096)  = 64 KiB packed bf16 codebook (B-fragment order):
//                byte = kt*2048 + h*1024 + l*16 + i*2
//                holds cb[kt*16 + (l&15)][h*32 + ((l>>4)&3)*8 + i]
//             float[16384..16896) = neg_half_c2[512]

static __device__ __forceinline__ unsigned int f2bf(float f) {
    unsigned int u = __float_as_uint(f);
    unsigned int r = u + 0x7FFFu + ((u >> 16) & 1u);   // RNE
    return r >> 16;
}

__global__ __launch_bounds__(256, 2) void vq_main(const float* __restrict__ x,
                                                  const float* __restrict__ cb,
                                                  float* __restrict__ out,
                                                  float* __restrict__ ws) {
    __shared__ f4 ldsv[4224];          // 67584 B: codebook + norms

    const int tid  = threadIdx.x;
    const int lane = tid & 63;
    const int wid  = tid >> 6;
    const int wave = blockIdx.x * 4 + wid;        // 0..2047
    const long rowbase = (long)wave * 64;         // 64 x-rows per wave (4 tiles)
    const int r15 = lane & 15;
    const int g   = lane >> 4;

    // ---- A fragments + fp32 row-norm partials (x touched once, registers)
    short8 A00, A01, A10, A11, A20, A21, A30, A31;
    float xn0 = 0.0f, xn1 = 0.0f, xn2 = 0.0f, xn3 = 0.0f;
    {
        const float* xa = x + (rowbase + r15) * DIMS + g * 8;
#define LOADA(FR, OFF, XN)                                                     \
        {                                                                      \
            const f4* p_ = (const f4*)(xa + (OFF));                            \
            f4 a_ = p_[0], b_ = p_[1];                                         \
            XN += a_[0]*a_[0] + a_[1]*a_[1] + a_[2]*a_[2] + a_[3]*a_[3]        \
                + b_[0]*b_[0] + b_[1]*b_[1] + b_[2]*b_[2] + b_[3]*b_[3];       \
            union { unsigned int u[4]; short8 s; } q_;                         \
            asm("v_cvt_pk_bf16_f32 %0, %1, %2" : "=v"(q_.u[0]) : "v"(a_[0]), "v"(a_[1])); \
            asm("v_cvt_pk_bf16_f32 %0, %1, %2" : "=v"(q_.u[1]) : "v"(a_[2]), "v"(a_[3])); \
            asm("v_cvt_pk_bf16_f32 %0, %1, %2" : "=v"(q_.u[2]) : "v"(b_[0]), "v"(b_[1])); \
            asm("v_cvt_pk_bf16_f32 %0, %1, %2" : "=v"(q_.u[3]) : "v"(b_[2]), "v"(b_[3])); \
            FR = q_.s;                                                         \
        }
        LOADA(A00, 0, xn0)
        LOADA(A01, 32, xn0)
        LOADA(A10, 16 * DIMS, xn1)
        LOADA(A11, 16 * DIMS + 32, xn1)
        LOADA(A20, 32 * DIMS, xn2)
        LOADA(A21, 32 * DIMS + 32, xn2)
        LOADA(A30, 48 * DIMS, xn3)
        LOADA(A31, 48 * DIMS + 32, xn3)
#undef LOADA
    }
    // full row norms: fold the 4 g-groups (lane keeps ||x_row(r15,tile)||^2)
    xn0 += __shfl_xor(xn0, 16, 64);  xn0 += __shfl_xor(xn0, 32, 64);
    xn1 += __shfl_xor(xn1, 16, 64);  xn1 += __shfl_xor(xn1, 32, 64);
    xn2 += __shfl_xor(xn2, 16, 64);  xn2 += __shfl_xor(xn2, 32, 64);
    xn3 += __shfl_xor(xn3, 16, 64);  xn3 += __shfl_xor(xn3, 32, 64);

    // ---- stage: pack fp32 codebook (L2-resident) -> bf16 B-fragment LDS
    {
#pragma unroll
        for (int i = 0; i < 16; ++i) {
            const int s = tid + i * 256;          // slice id; LDS byte = s*16
            const int kt = s >> 7, rest = s & 127;
            const int h = rest >> 6, l = rest & 63;
            const int row = kt * 16 + (l & 15);
            const int col = h * 32 + ((l >> 4) & 3) * 8;
            const f4* p = (const f4*)(cb + row * DIMS + col);
            f4 u0 = p[0], u1 = p[1];
            union { unsigned int u[4]; f4 f; } q;
            q.u[0] = (f2bf(u0[1]) << 16) | f2bf(u0[0]);
            q.u[1] = (f2bf(u0[3]) << 16) | f2bf(u0[2]);
            q.u[2] = (f2bf(u1[1]) << 16) | f2bf(u1[0]);
            q.u[3] = (f2bf(u1[3]) << 16) | f2bf(u1[2]);
            ldsv[s] = q.f;
        }
        // norms: thread handles rows tid and tid+256 (deterministic serial sum)
        float* ldsn_w = (float*)ldsv + 16384;
#pragma unroll
        for (int rr = 0; rr < 2; ++rr) {
            const int r = tid + rr * 256;
            const f4* p = (const f4*)(cb + r * DIMS);
            float s0 = 0.0f;
#pragma unroll
            for (int i = 0; i < 16; ++i) {
                f4 v = p[i];
                s0 += v[0]*v[0] + v[1]*v[1] + v[2]*v[2] + v[3]*v[3];
            }
            ldsn_w[r] = -0.5f * s0;
        }
    }

    __syncthreads();   // LDS codebook + norms ready

    // ---- mantissa-packed argmax state (low 9 bits of score carry k)
    float bv00 = -3.4e38f, bv01 = -3.4e38f, bv02 = -3.4e38f, bv03 = -3.4e38f;
    float bv10 = -3.4e38f, bv11 = -3.4e38f, bv12 = -3.4e38f, bv13 = -3.4e38f;
    float bv20 = -3.4e38f, bv21 = -3.4e38f, bv22 = -3.4e38f, bv23 = -3.4e38f;
    float bv30 = -3.4e38f, bv31 = -3.4e38f, bv32 = -3.4e38f, bv33 = -3.4e38f;

    const char*  ldsb = (const char*)ldsv;
    const float* ldsn = (const float*)ldsv + 16384;
    const int laneoff = lane * 16;

#define PKMAX(BV, S)                                                           \
    BV = fmaxf(BV, __uint_as_float((__float_as_uint(S) & 0xFFFFFE00u) | kr));

#pragma unroll
    for (int kt = 0; kt < 32; ++kt) {
        short8 b0 = *(const short8*)(ldsb + kt * 2048 + laneoff);
        short8 b1 = *(const short8*)(ldsb + kt * 2048 + 1024 + laneoff);
        float ic = ldsn[kt * 16 + r15];          // conflict-free broadcast read
        f32x4 init = {ic, ic, ic, ic};
        f32x4 a0 = __builtin_amdgcn_mfma_f32_16x16x32_bf16(A00, b0, init, 0, 0, 0);
        a0       = __builtin_amdgcn_mfma_f32_16x16x32_bf16(A01, b1, a0,  0, 0, 0);
        f32x4 a1 = __builtin_amdgcn_mfma_f32_16x16x32_bf16(A10, b0, init, 0, 0, 0);
        a1       = __builtin_amdgcn_mfma_f32_16x16x32_bf16(A11, b1, a1,  0, 0, 0);
        f32x4 a2 = __builtin_amdgcn_mfma_f32_16x16x32_bf16(A20, b0, init, 0, 0, 0);
        a2       = __builtin_amdgcn_mfma_f32_16x16x32_bf16(A21, b1, a2,  0, 0, 0);
        f32x4 a3 = __builtin_amdgcn_mfma_f32_16x16x32_bf16(A30, b0, init, 0, 0, 0);
        a3       = __builtin_amdgcn_mfma_f32_16x16x32_bf16(A31, b1, a3,  0, 0, 0);
        const unsigned int kr = (unsigned int)(kt * 16 + r15);
        PKMAX(bv00, a0[0]) PKMAX(bv01, a0[1]) PKMAX(bv02, a0[2]) PKMAX(bv03, a0[3])
        PKMAX(bv10, a1[0]) PKMAX(bv11, a1[1]) PKMAX(bv12, a1[2]) PKMAX(bv13, a1[3])
        PKMAX(bv20, a2[0]) PKMAX(bv21, a2[1]) PKMAX(bv22, a2[2]) PKMAX(bv23, a2[3])
        PKMAX(bv30, a3[0]) PKMAX(bv31, a3[1]) PKMAX(bv32, a3[2]) PKMAX(bv33, a3[3])
    }
#undef PKMAX

    // ---- argmax reduce across the 16 lanes of each row-group (k dimension)
#pragma unroll
    for (int st = 0; st < 4; ++st) {
        const int m = 1 << st;
        bv00 = fmaxf(bv00, __shfl_xor(bv00, m, 64));
        bv01 = fmaxf(bv01, __shfl_xor(bv01, m, 64));
        bv02 = fmaxf(bv02, __shfl_xor(bv02, m, 64));
        bv03 = fmaxf(bv03, __shfl_xor(bv03, m, 64));
        bv10 = fmaxf(bv10, __shfl_xor(bv10, m, 64));
        bv11 = fmaxf(bv11, __shfl_xor(bv11, m, 64));
        bv12 = fmaxf(bv12, __shfl_xor(bv12, m, 64));
        bv13 = fmaxf(bv13, __shfl_xor(bv13, m, 64));
        bv20 = fmaxf(bv20, __shfl_xor(bv20, m, 64));
        bv21 = fmaxf(bv21, __shfl_xor(bv21, m, 64));
        bv22 = fmaxf(bv22, __shfl_xor(bv22, m, 64));
        bv23 = fmaxf(bv23, __shfl_xor(bv23, m, 64));
        bv30 = fmaxf(bv30, __shfl_xor(bv30, m, 64));
        bv31 = fmaxf(bv31, __shfl_xor(bv31, m, 64));
        bv32 = fmaxf(bv32, __shfl_xor(bv32, m, 64));
        bv33 = fmaxf(bv33, __shfl_xor(bv33, m, 64));
    }

    // ---- epilogue: pure gather -> store (no x re-read)
    const int orow = lane >> 2;        // 0..15: row within tile
    const int cseg = lane & 3;         // 16-float column segment
    const int j2   = orow & 3;
#define SEL(T) (int)(__float_as_uint(j2 == 0 ? bv##T##0 : j2 == 1 ? bv##T##1 : \
                                     j2 == 2 ? bv##T##2 : bv##T##3) & 511u)
    const int idx0 = SEL(0);
    const int idx1 = SEL(1);
    const int idx2 = SEL(2);
    const int idx3 = SEL(3);
#undef SEL

#define EPI(IDX, TOFF)                                                     \
    {                                                                      \
        const long row_ = rowbase + (TOFF) + orow;                         \
        const f4* cq_ = (const f4*)(cb + (long)(IDX) * DIMS + cseg * 16);  \
        f4* op_      = (f4*)(out + row_ * DIMS + cseg * 16);               \
        _Pragma("unroll")                                                  \
        for (int u = 0; u < 4; ++u) op_[u] = cq_[u];                       \
    }
    EPI(idx0, 0)
    EPI(idx1, 16)
    EPI(idx2, 32)
    EPI(idx3, 48)
#undef EPI

    // ---- loss from scores: ||q-x||^2 = ||x||^2 - 2*best  (no x re-read)
    float lsum = 0.0f;
    if (g == (r15 >> 2)) {             // this lane's bv row (g*4+j') == its r15 row
        const int jp = r15 & 3;
#define SSEL(T) __uint_as_float(__float_as_uint(jp == 0 ? bv##T##0 : jp == 1 ? bv##T##1 : \
                                jp == 2 ? bv##T##2 : bv##T##3) & 0xFFFFFE00u)
        lsum = (xn0 - 2.0f * SSEL(0)) + (xn1 - 2.0f * SSEL(1))
             + (xn2 - 2.0f * SSEL(2)) + (xn3 - 2.0f * SSEL(3));
#undef SSEL
    }
#pragma unroll
    for (int s = 0; s < 6; ++s) lsum += __shfl_xor(lsum, 1 << s, 64);

    __syncthreads();                   // all waves done reading lds codebook
    float* lsred = (float*)ldsv;
    if (lane == 0) lsred[wid] = lsum;
    __syncthreads();
    if (tid == 0) {
        ws[blockIdx.x] = lsred[0] + lsred[1] + lsred[2] + lsred[3];
    }
}

__global__ __launch_bounds__(256) void vq_final(const float* __restrict__ ws,
                                                float* __restrict__ out) {
    const int t = threadIdx.x;
    float s = ws[t] + ws[t + 256];
#pragma unroll
    for (int st = 0; st < 6; ++st) s += __shfl_xor(s, 1 << st, 64);
    __shared__ float w2[4];
    if ((t & 63) == 0) w2[t >> 6] = s;
    __syncthreads();
    if (t == 0) {
        float total = w2[0] + w2[1] + w2[2] + w2[3];
        out[OUT_Q] = 1.25f * total / 8388608.0f;
    }
}

extern "C" void kernel_launch(void* const* d_in, const int* in_sizes, int n_in,
                              void* d_out, int out_size, void* d_ws, size_t ws_size,
                              hipStream_t stream) {
    const float* x  = (const float*)d_in[0];
    const float* cb = (const float*)d_in[1];
    float* out = (float*)d_out;
    float* ws  = (float*)d_ws;
    vq_main<<<512, 256, 0, stream>>>(x, cb, out, ws);
    vq_final<<<1, 256, 0, stream>>>(ws, out);
}